// Round 13
// baseline (493.440 us; speedup 1.0000x reference)
//
#include <hip/hip_runtime.h>

#define NN 100000
#define NE 2500000
#define BK_SHIFT 7
#define BK_NODES 128
#define NBUCK ((NN + BK_NODES - 1) / BK_NODES)   // 782
#define TILE 4096
#define NTILES ((NE + TILE - 1) / TILE)     // 611
#define SRC_MASK 0x1FFFF                    // 17 bits, NN < 131072

// ---------------- CSR build: tile hist -> bucket totals -> scan -> direct-write binning ----------------

__global__ __launch_bounds__(256) void k_tilecnt2(const int* __restrict__ src,
                                                  const int* __restrict__ dst,
                                                  int* __restrict__ tot_d, int* __restrict__ tot_s,
                                                  int E) {
    __shared__ int cd[NBUCK];
    __shared__ int cs[NBUCK];
    int base = blockIdx.x * TILE;
    for (int i = threadIdx.x; i < NBUCK; i += 256) { cd[i] = 0; cs[i] = 0; }
    __syncthreads();
#pragma unroll
    for (int k = 0; k < 16; ++k) {
        int idx = base + threadIdx.x + k * 256;
        if (idx < E) {
            atomicAdd(&cd[dst[idx] >> BK_SHIFT], 1);
            atomicAdd(&cs[src[idx] >> BK_SHIFT], 1);
        }
    }
    __syncthreads();
    for (int i = threadIdx.x; i < NBUCK; i += 256) {
        int c = cd[i]; if (c) atomicAdd(&tot_d[i], c);
        c = cs[i];     if (c) atomicAdd(&tot_s[i], c);
    }
}

__global__ __launch_bounds__(1024) void k_bucket_scan(const int* __restrict__ tot_d,
                                                      const int* __restrict__ tot_s,
                                                      int* __restrict__ base_d, int* __restrict__ base_s,
                                                      int* __restrict__ cursor_d, int* __restrict__ cursor_s,
                                                      int* __restrict__ row_ptr, int E) {
    __shared__ int sh[1024];
    int tid = threadIdx.x;
    int v = (tid < NBUCK) ? tot_d[tid] : 0;
    sh[tid] = v;
    __syncthreads();
#pragma unroll
    for (int off = 1; off < 1024; off <<= 1) {
        int t = (tid >= off) ? sh[tid - off] : 0;
        __syncthreads();
        sh[tid] += t;
        __syncthreads();
    }
    if (tid < NBUCK) { int ex = sh[tid] - v; base_d[tid] = ex; cursor_d[tid] = ex; }
    if (tid == 0) { base_d[NBUCK] = E; row_ptr[NN] = E; }
    __syncthreads();
    v = (tid < NBUCK) ? tot_s[tid] : 0;
    sh[tid] = v;
    __syncthreads();
#pragma unroll
    for (int off = 1; off < 1024; off <<= 1) {
        int t = (tid >= off) ? sh[tid - off] : 0;
        __syncthreads();
        sh[tid] += t;
        __syncthreads();
    }
    if (tid < NBUCK) { int ex = sh[tid] - v; base_s[tid] = ex; cursor_s[tid] = ex; }
    if (tid == 0) base_s[NBUCK] = E;
}

__global__ __launch_bounds__(256) void k_binpass2(
    const int* __restrict__ src, const int* __restrict__ dst, const float* __restrict__ ew,
    int* __restrict__ cursor_d, int* __restrict__ cursor_s,
    int2* __restrict__ stage2, unsigned char* __restrict__ stage_s, int E) {
    __shared__ int cnt_d[NBUCK];
    __shared__ int gpos_d[NBUCK];
    __shared__ int cnt_s[NBUCK];
    __shared__ int gpos_s[NBUCK];

    int base = blockIdx.x * TILE;
    for (int i = threadIdx.x; i < NBUCK; i += 256) { cnt_d[i] = 0; cnt_s[i] = 0; }
    __syncthreads();

    int w0[16]; float w1[16]; int pd[16]; int rs[16];
#pragma unroll
    for (int k = 0; k < 16; ++k) {
        int idx = base + threadIdx.x + k * 256;
        pd[k] = -1;
        if (idx < E) {
            int s = src[idx], d = dst[idx];
            w1[k] = ew[idx];
            int bd = d >> BK_SHIFT;
            w0[k] = s | ((d & (BK_NODES - 1)) << 17);
            int rd = atomicAdd(&cnt_d[bd], 1);
            pd[k] = bd | (rd << 10);
            rs[k] = atomicAdd(&cnt_s[s >> BK_SHIFT], 1);
        }
    }
    __syncthreads();

    for (int i = threadIdx.x; i < NBUCK; i += 256) {
        int c = cnt_d[i]; if (c) gpos_d[i] = atomicAdd(&cursor_d[i], c);
        c = cnt_s[i];     if (c) gpos_s[i] = atomicAdd(&cursor_s[i], c);
    }
    __syncthreads();

#pragma unroll
    for (int k = 0; k < 16; ++k) {
        if (pd[k] >= 0) {
            int bd = pd[k] & 1023, rd = pd[k] >> 10;
            stage2[gpos_d[bd] + rd] = make_int2(w0[k], __float_as_int(w1[k]));
            int s = w0[k] & SRC_MASK;
            stage_s[gpos_s[s >> BK_SHIFT] + rs[k]] = (unsigned char)(s & (BK_NODES - 1));
        }
    }
}

__global__ __launch_bounds__(256) void k_prep_src(
    const int* __restrict__ base_s, const unsigned char* __restrict__ stage_s, const float* __restrict__ x,
    float* __restrict__ no, float* __restrict__ xs, int N) {
    __shared__ int cnt[BK_NODES];
    int b = blockIdx.x;
    int beg = base_s[b], end = base_s[b + 1];
    if (threadIdx.x < BK_NODES) cnt[threadIdx.x] = 0;
    __syncthreads();
    for (int j = beg + threadIdx.x; j < end; j += 256) atomicAdd(&cnt[stage_s[j]], 1);
    __syncthreads();
    if (threadIdx.x < BK_NODES) {
        int n = (b << BK_SHIFT) + threadIdx.x;
        if (n < N) {
            float nov = rsqrtf(fmaxf((float)cnt[threadIdx.x], 1.0f));
            no[n] = nov;
#pragma unroll
            for (int f = 0; f < 7; ++f) xs[n * 8 + f] = x[n * 7 + f] * nov;
            xs[n * 8 + 7] = 0.f;
        }
    }
}

__global__ __launch_bounds__(256) void k_scatter2(
    const int* __restrict__ base_d, const int2* __restrict__ stage2,
    int* __restrict__ row_ptr, float* __restrict__ ni,
    int* __restrict__ csr_src, float* __restrict__ csr_w, int N) {
    __shared__ int cnt[BK_NODES];
    __shared__ int scn[BK_NODES];
    __shared__ int cur[BK_NODES];
    int b = blockIdx.x;
    int beg = base_d[b], end = base_d[b + 1];
    if (threadIdx.x < BK_NODES) cnt[threadIdx.x] = 0;
    __syncthreads();
    for (int j = beg + threadIdx.x; j < end; j += 256) atomicAdd(&cnt[stage2[j].x >> 17], 1);
    __syncthreads();
    int v = (threadIdx.x < BK_NODES) ? cnt[threadIdx.x] : 0;
    if (threadIdx.x < BK_NODES) scn[threadIdx.x] = v;
    __syncthreads();
#pragma unroll
    for (int off = 1; off < BK_NODES; off <<= 1) {
        int t = (threadIdx.x < BK_NODES && threadIdx.x >= off) ? scn[threadIdx.x - off] : 0;
        __syncthreads();
        if (threadIdx.x < BK_NODES) scn[threadIdx.x] += t;
        __syncthreads();
    }
    if (threadIdx.x < BK_NODES) {
        int ex = scn[threadIdx.x] - v;
        cur[threadIdx.x] = beg + ex;
        int n = (b << BK_SHIFT) + threadIdx.x;
        if (n < N) {
            row_ptr[n] = beg + ex;
            ni[n] = rsqrtf(fmaxf((float)v, 1.0f));
        }
    }
    __syncthreads();
    for (int j = beg + threadIdx.x; j < end; j += 256) {
        int2 t = stage2[j];
        int dl = t.x >> 17;
        int pos = atomicAdd(&cur[dl], 1);
        csr_src[pos] = t.x & SRC_MASK;
        csr_w[pos] = __int_as_float(t.y);
    }
}

// ---------------- fused layers ----------------
// h between 32-wide layers is CHUNK-MAJOR: hc[c][N][8], c=0..3 (per-chunk table 3.2MB, L2-resident).
// All accumulation replicates round-8's exact fp32 op order (bit-identical results).

// layer 1: round-8 verbatim, store chunk-major.
__global__ __launch_bounds__(256) void k_layer1(
    const int* __restrict__ rp, const int* __restrict__ csr_src, const float* __restrict__ csr_w,
    const float* __restrict__ xs, const float* __restrict__ ni, const float* __restrict__ no,
    const float* __restrict__ W1, const float* __restrict__ b1, float* __restrict__ h1c, int N) {
    __shared__ float sW[7 * 32];
    __shared__ float sb[32];
    __shared__ float sh7[32][8];
    for (int i = threadIdx.x; i < 7 * 32; i += 256) sW[i] = W1[i];
    if (threadIdx.x < 32) sb[threadIdx.x] = b1[threadIdx.x];

    int g = threadIdx.x >> 3, lane = threadIdx.x & 7;
    int node = blockIdx.x * 32 + g;
    float acc = 0.f;
    if (node < N) {
        int beg = rp[node], end = rp[node + 1];
        for (int j0 = beg; j0 < end; j0 += 8) {
            int ms = 0; float mw = 0.f;
            if (j0 + lane < end) {
                ms = csr_src[j0 + lane];
                mw = csr_w[j0 + lane];
            }
            int m = end - j0; if (m > 8) m = 8;
            float a0 = 0.f, a1 = 0.f, a2 = 0.f, a3 = 0.f;
            int k = 0;
            for (; k + 4 <= m; k += 4) {
                int s0 = __shfl(ms, k, 8);     float w0 = __shfl(mw, k, 8);
                int s1 = __shfl(ms, k + 1, 8); float w1 = __shfl(mw, k + 1, 8);
                int s2 = __shfl(ms, k + 2, 8); float w2 = __shfl(mw, k + 2, 8);
                int s3 = __shfl(ms, k + 3, 8); float w3 = __shfl(mw, k + 3, 8);
                a0 += xs[s0 * 8 + lane] * w0;
                a1 += xs[s1 * 8 + lane] * w1;
                a2 += xs[s2 * 8 + lane] * w2;
                a3 += xs[s3 * 8 + lane] * w3;
            }
            for (; k < m; ++k) {
                int s = __shfl(ms, k, 8);
                float w = __shfl(mw, k, 8);
                a0 += xs[s * 8 + lane] * w;
            }
            acc += (a0 + a1) + (a2 + a3);
        }
        acc *= ni[node];
    }
    sh7[g][lane] = acc;
    __syncthreads();

    int g2 = threadIdx.x >> 5, l32 = threadIdx.x & 31;
#pragma unroll
    for (int t = 0; t < 4; ++t) {
        int nl = t * 8 + g2;
        int node2 = blockIdx.x * 32 + nl;
        if (node2 < N) {
            float o = sb[l32];
#pragma unroll
            for (int k = 0; k < 7; ++k) o += sh7[nl][k] * sW[k * 32 + l32];
            h1c[(size_t)(l32 >> 3) * N * 8 + (size_t)node2 * 8 + (l32 & 7)] =
                fmaxf(o, 0.f) * no[node2];
        }
    }
}

// 8-edge sub-batch, replicating round-8's quad/single schedule.
// Shuffle width 8 == divergence granularity (per-node group) -> sources always active.
__device__ __forceinline__ void proc8(int msr, int mm, const float* __restrict__ tbl, int lane,
                                      float& a0, float& a1, float& a2, float& a3) {
    if (mm >= 8) {
        a0 += tbl[__shfl(msr, 0, 8) * 8 + lane];
        a1 += tbl[__shfl(msr, 1, 8) * 8 + lane];
        a2 += tbl[__shfl(msr, 2, 8) * 8 + lane];
        a3 += tbl[__shfl(msr, 3, 8) * 8 + lane];
        a0 += tbl[__shfl(msr, 4, 8) * 8 + lane];
        a1 += tbl[__shfl(msr, 5, 8) * 8 + lane];
        a2 += tbl[__shfl(msr, 6, 8) * 8 + lane];
        a3 += tbl[__shfl(msr, 7, 8) * 8 + lane];
    } else {
        int kl = 0;
        for (; kl + 4 <= mm; kl += 4) {
            a0 += tbl[__shfl(msr, kl, 8) * 8 + lane];
            a1 += tbl[__shfl(msr, kl + 1, 8) * 8 + lane];
            a2 += tbl[__shfl(msr, kl + 2, 8) * 8 + lane];
            a3 += tbl[__shfl(msr, kl + 3, 8) * 8 + lane];
        }
        for (; kl < mm; ++kl) a0 += tbl[__shfl(msr, kl, 8) * 8 + lane];
    }
}

// chunked aggregation, 2-NODE INTERLEAVED: each 8-lane group walks two nodes'
// edge lists simultaneously (independent register state -> 2x latency chains in
// flight). Per-node accumulation schedule is round-12 verbatim (bit-identical).
__global__ __launch_bounds__(256) void k_aggc(
    const int* __restrict__ rp, const int* __restrict__ csr_src, const float* __restrict__ hc_in,
    const float* __restrict__ ni, float* __restrict__ aggout, int N) {
    int g = threadIdx.x >> 3, lane = threadIdx.x & 7;
    int c = blockIdx.y;
    const float* tbl = hc_in + (size_t)c * N * 8;
    int nodeA = blockIdx.x * 64 + g;
    int nodeB = nodeA + 32;
    int jA = 0, endA = 0, jB = 0, endB = 0;
    if (nodeA < N) { jA = rp[nodeA]; endA = rp[nodeA + 1]; }
    if (nodeB < N) { jB = rp[nodeB]; endB = rp[nodeB + 1]; }
    float accA = 0.f, accB = 0.f;

    while (jA < endA || jB < endB) {
        bool hA = jA < endA, hB = jB < endB;
        int mA = 0, mB = 0;
        int A0 = 0, A1 = 0, A2 = 0, A3 = 0;
        int B0 = 0, B1 = 0, B2 = 0, B3 = 0;
        if (hA) {
            mA = endA - jA; if (mA > 32) mA = 32;
            A0 = (jA + lane < endA) ? csr_src[jA + lane] : 0;
            A1 = (jA + 8 + lane < endA) ? csr_src[jA + 8 + lane] : 0;
            A2 = (jA + 16 + lane < endA) ? csr_src[jA + 16 + lane] : 0;
            A3 = (jA + 24 + lane < endA) ? csr_src[jA + 24 + lane] : 0;
        }
        if (hB) {
            mB = endB - jB; if (mB > 32) mB = 32;
            B0 = (jB + lane < endB) ? csr_src[jB + lane] : 0;
            B1 = (jB + 8 + lane < endB) ? csr_src[jB + 8 + lane] : 0;
            B2 = (jB + 16 + lane < endB) ? csr_src[jB + 16 + lane] : 0;
            B3 = (jB + 24 + lane < endB) ? csr_src[jB + 24 + lane] : 0;
        }
        float a0 = 0.f, a1 = 0.f, a2 = 0.f, a3 = 0.f;
        float b0 = 0.f, b1 = 0.f, b2 = 0.f, b3 = 0.f;
        if (hA) {
            proc8(A0, mA, tbl, lane, a0, a1, a2, a3);
            if (mA > 8)  proc8(A1, mA - 8, tbl, lane, a0, a1, a2, a3);
            if (mA > 16) proc8(A2, mA - 16, tbl, lane, a0, a1, a2, a3);
            if (mA > 24) proc8(A3, mA - 24, tbl, lane, a0, a1, a2, a3);
        }
        if (hB) {
            proc8(B0, mB, tbl, lane, b0, b1, b2, b3);
            if (mB > 8)  proc8(B1, mB - 8, tbl, lane, b0, b1, b2, b3);
            if (mB > 16) proc8(B2, mB - 16, tbl, lane, b0, b1, b2, b3);
            if (mB > 24) proc8(B3, mB - 24, tbl, lane, b0, b1, b2, b3);
        }
        if (hA) { accA += (a0 + a1) + (a2 + a3); jA += 32; }
        if (hB) { accB += (b0 + b1) + (b2 + b3); jB += 32; }
    }
    if (nodeA < N)
        aggout[(size_t)c * N * 8 + (size_t)nodeA * 8 + lane] = accA * ni[nodeA];
    if (nodeB < N)
        aggout[(size_t)c * N * 8 + (size_t)nodeB * 8 + lane] = accB * ni[nodeB];
}

// matmul epilogue for layer 2 (in-place safe: reads all features into LDS before barrier).
__global__ __launch_bounds__(256) void k_mm2(
    const float* __restrict__ agg, const float* __restrict__ W, const float* __restrict__ bia,
    const float* __restrict__ no, float* __restrict__ hc_out, int N) {
    __shared__ float sW[32 * 32];
    __shared__ float sb[32];
    __shared__ float shv[8][32];
    for (int i = threadIdx.x; i < 1024; i += 256) sW[i] = W[i];
    if (threadIdx.x < 32) sb[threadIdx.x] = bia[threadIdx.x];
    int g = threadIdx.x >> 5, lane = threadIdx.x & 31;
    int n = blockIdx.x * 8 + g;
    if (n < N)
        shv[g][lane] = agg[(size_t)(lane >> 3) * N * 8 + (size_t)n * 8 + (lane & 7)];
    __syncthreads();
    if (n < N) {
        float o = sb[lane];
#pragma unroll
        for (int k = 0; k < 32; ++k) o += shv[g][k] * sW[k * 32 + lane];
        hc_out[(size_t)(lane >> 3) * N * 8 + (size_t)n * 8 + (lane & 7)] =
            fmaxf(o, 0.f) * no[n];
    }
}

// matmul epilogue for layer 3 + W4 pre-multiply -> h4pre.
__global__ __launch_bounds__(256) void k_mm3(
    const float* __restrict__ agg, const float* __restrict__ W3, const float* __restrict__ b3,
    const float* __restrict__ W4, const float* __restrict__ no, float2* __restrict__ h4pre, int N) {
    __shared__ float sW[32 * 32];
    __shared__ float sb[32];
    __shared__ float sW4[64];
    __shared__ float shv[8][32];
    for (int i = threadIdx.x; i < 1024; i += 256) sW[i] = W3[i];
    if (threadIdx.x < 32) sb[threadIdx.x] = b3[threadIdx.x];
    if (threadIdx.x < 64) sW4[threadIdx.x] = W4[threadIdx.x];
    int g = threadIdx.x >> 5, lane = threadIdx.x & 31;
    int n = blockIdx.x * 8 + g;
    if (n < N)
        shv[g][lane] = agg[(size_t)(lane >> 3) * N * 8 + (size_t)n * 8 + (lane & 7)];
    __syncthreads();
    if (n < N) {
        float o = sb[lane];
#pragma unroll
        for (int k = 0; k < 32; ++k) o += shv[g][k] * sW[k * 32 + lane];
        float t = fmaxf(o, 0.f) * no[n];
        float px = t * sW4[lane * 2 + 0];
        float py = t * sW4[lane * 2 + 1];
#pragma unroll
        for (int off = 16; off; off >>= 1) {
            px += __shfl_xor(px, off, 32);
            py += __shfl_xor(py, off, 32);
        }
        if (lane == 0) h4pre[n] = make_float2(px, py);
    }
}

__global__ void k_agg4(const int* __restrict__ rp, const int* __restrict__ csr_src,
                       const float2* __restrict__ h4pre, const float* __restrict__ ni,
                       float2* __restrict__ agg2, int N) {
    int n = blockIdx.x * blockDim.x + threadIdx.x;
    if (n >= N) return;
    int beg = rp[n], end = rp[n + 1];
    float ax0 = 0.f, ay0 = 0.f, ax1 = 0.f, ay1 = 0.f;
    int j = beg;
    for (; j + 2 <= end; j += 2) {
        int s0 = csr_src[j], s1 = csr_src[j + 1];
        float2 v0 = h4pre[s0];
        float2 v1 = h4pre[s1];
        ax0 += v0.x; ay0 += v0.y;
        ax1 += v1.x; ay1 += v1.y;
    }
    if (j < end) {
        float2 v = h4pre[csr_src[j]];
        ax0 += v.x; ay0 += v.y;
    }
    float w = ni[n];
    agg2[n] = make_float2((ax0 + ax1) * w, (ay0 + ay1) * w);
}

__global__ void k_pool(const float2* __restrict__ agg2, const int* __restrict__ gid,
                       const float* __restrict__ b4, float* __restrict__ out, int N) {
    int g = blockIdx.x;
    int lo = 0, hi = N;
    while (lo < hi) { int m = (lo + hi) >> 1; if (gid[m] < g) lo = m + 1; else hi = m; }
    int start = lo;
    int lo2 = start, hi2 = N;
    while (lo2 < hi2) { int m = (lo2 + hi2) >> 1; if (gid[m] < g + 1) lo2 = m + 1; else hi2 = m; }
    int end = lo2;
    float sx = 0.f, sy = 0.f;
    for (int n = start + threadIdx.x; n < end; n += 64) {
        float2 v = agg2[n];
        sx += v.x;
        sy += v.y;
    }
#pragma unroll
    for (int off = 32; off; off >>= 1) {
        sx += __shfl_down(sx, off, 64);
        sy += __shfl_down(sy, off, 64);
    }
    if (threadIdx.x == 0) {
        int cnt = end - start;
        float inv = 1.0f / fmaxf((float)cnt, 1.0f);
        float scale = (float)cnt * inv;  // 0 if empty, else 1
        out[g * 2 + 0] = sx * inv + b4[0] * scale;
        out[g * 2 + 1] = sy * inv + b4[1] * scale;
    }
}

// ---------------- launch ----------------

extern "C" void kernel_launch(void* const* d_in, const int* in_sizes, int n_in,
                              void* d_out, int out_size, void* d_ws, size_t ws_size,
                              hipStream_t stream) {
    const float* x   = (const float*)d_in[0];
    const float* e   = (const float*)d_in[1];
    const float* W1  = (const float*)d_in[2];
    const float* b1  = (const float*)d_in[3];
    const float* W2  = (const float*)d_in[4];
    const float* b2  = (const float*)d_in[5];
    const float* W3  = (const float*)d_in[6];
    const float* b3  = (const float*)d_in[7];
    const float* W4  = (const float*)d_in[8];
    const float* b4  = (const float*)d_in[9];
    const int*   src = (const int*)d_in[10];
    const int*   dst = (const int*)d_in[11];
    const int*   gid = (const int*)d_in[12];
    float* out = (float*)d_out;

    const int N = NN, E = NE;
    const int G = out_size / 2;

    int* ws_i = (int*)d_ws;
    int* tot_d    = ws_i;                         // 1024
    int* tot_s    = ws_i + 1024;                  // 1024
    int* base_d   = ws_i + 2048;                  // 1024 (need 783)
    int* base_s   = ws_i + 3072;                  // 1024
    int* cursor_d = ws_i + 4096;                  // 1024
    int* cursor_s = ws_i + 5120;                  // 1024
    int* row_ptr  = ws_i + 6144;                  // N+4
    int* csr_src  = ws_i + 6144 + (size_t)N + 4;  // E
    float* csr_w  = (float*)(ws_i + 6144 + (size_t)N + 4 + (size_t)E); // E
    unsigned char* stage_s = (unsigned char*)csr_w;  // alias: dead before csr_w written

    float* fbase = (float*)(ws_i + 6144 + (size_t)N + 4 + 2 * (size_t)E);
    float* no_b  = fbase;                          // N
    float* ni_b  = fbase + (size_t)N;              // N
    float* xs    = fbase + (size_t)2 * N;          // 8N
    float* h1c   = fbase + (size_t)10 * N;         // 32N (chunk-major [4][N][8])
    float* h2c   = fbase + (size_t)42 * N;         // 32N (chunk-major; doubles as layer-2 agg, in-place)
    float2* h4pre = (float2*)(fbase + (size_t)74 * N); // 2N
    float2* agg2  = (float2*)(fbase + (size_t)76 * N); // 2N
    // stage2 aliased over h1c/h2c (2E ints = 5M <= 64N; dead before layer1 writes h1c)
    int2* stage2 = (int2*)(fbase + (size_t)10 * N);
    // layer-3 agg buffer reuses h1c (dead after layer-2 aggregation)
    float* agg3 = h1c;

    // zero only the bucket-total arrays (8 KB)
    hipMemsetAsync(ws_i, 0, 2048 * sizeof(int), stream);

    k_tilecnt2<<<NTILES, 256, 0, stream>>>(src, dst, tot_d, tot_s, E);
    k_bucket_scan<<<1, 1024, 0, stream>>>(tot_d, tot_s, base_d, base_s, cursor_d, cursor_s, row_ptr, E);
    k_binpass2<<<NTILES, 256, 0, stream>>>(src, dst, e, cursor_d, cursor_s, stage2, stage_s, E);
    k_prep_src<<<NBUCK, 256, 0, stream>>>(base_s, stage_s, x, no_b, xs, N);
    k_scatter2<<<NBUCK, 256, 0, stream>>>(base_d, stage2, row_ptr, ni_b, csr_src, csr_w, N);

    dim3 gAgg((N + 63) / 64, 4);
    k_layer1<<<(N + 31) / 32, 256, 0, stream>>>(row_ptr, csr_src, csr_w, xs, ni_b, no_b, W1, b1, h1c, N);
    k_aggc<<<gAgg, 256, 0, stream>>>(row_ptr, csr_src, h1c, ni_b, h2c, N);
    k_mm2<<<(N + 7) / 8, 256, 0, stream>>>(h2c, W2, b2, no_b, h2c, N);
    k_aggc<<<gAgg, 256, 0, stream>>>(row_ptr, csr_src, h2c, ni_b, agg3, N);
    k_mm3<<<(N + 7) / 8, 256, 0, stream>>>(agg3, W3, b3, W4, no_b, h4pre, N);
    k_agg4<<<(N + 255) / 256, 256, 0, stream>>>(row_ptr, csr_src, h4pre, ni_b, agg2, N);
    k_pool<<<G, 64, 0, stream>>>(agg2, gid, b4, out, N);
}

// Round 14
// 461.793 us; speedup vs baseline: 1.0685x; 1.0685x over previous
//
#include <hip/hip_runtime.h>

#define NN 100000
#define NE 2500000
#define BK_SHIFT 7
#define BK_NODES 128
#define NBUCK ((NN + BK_NODES - 1) / BK_NODES)   // 782
#define TILE 4096
#define NTILES ((NE + TILE - 1) / TILE)     // 611
#define SRC_MASK 0x1FFFF                    // 17 bits, NN < 131072

// ---------------- CSR build: tile hist -> bucket totals -> scan -> direct-write binning ----------------

__global__ __launch_bounds__(256) void k_tilecnt2(const int* __restrict__ src,
                                                  const int* __restrict__ dst,
                                                  int* __restrict__ tot_d, int* __restrict__ tot_s,
                                                  int E) {
    __shared__ int cd[NBUCK];
    __shared__ int cs[NBUCK];
    int base = blockIdx.x * TILE;
    for (int i = threadIdx.x; i < NBUCK; i += 256) { cd[i] = 0; cs[i] = 0; }
    __syncthreads();
#pragma unroll
    for (int k = 0; k < 16; ++k) {
        int idx = base + threadIdx.x + k * 256;
        if (idx < E) {
            atomicAdd(&cd[dst[idx] >> BK_SHIFT], 1);
            atomicAdd(&cs[src[idx] >> BK_SHIFT], 1);
        }
    }
    __syncthreads();
    for (int i = threadIdx.x; i < NBUCK; i += 256) {
        int c = cd[i]; if (c) atomicAdd(&tot_d[i], c);
        c = cs[i];     if (c) atomicAdd(&tot_s[i], c);
    }
}

__global__ __launch_bounds__(1024) void k_bucket_scan(const int* __restrict__ tot_d,
                                                      const int* __restrict__ tot_s,
                                                      int* __restrict__ base_d, int* __restrict__ base_s,
                                                      int* __restrict__ cursor_d, int* __restrict__ cursor_s,
                                                      int* __restrict__ row_ptr, int E) {
    __shared__ int sh[1024];
    int tid = threadIdx.x;
    int v = (tid < NBUCK) ? tot_d[tid] : 0;
    sh[tid] = v;
    __syncthreads();
#pragma unroll
    for (int off = 1; off < 1024; off <<= 1) {
        int t = (tid >= off) ? sh[tid - off] : 0;
        __syncthreads();
        sh[tid] += t;
        __syncthreads();
    }
    if (tid < NBUCK) { int ex = sh[tid] - v; base_d[tid] = ex; cursor_d[tid] = ex; }
    if (tid == 0) { base_d[NBUCK] = E; row_ptr[NN] = E; }
    __syncthreads();
    v = (tid < NBUCK) ? tot_s[tid] : 0;
    sh[tid] = v;
    __syncthreads();
#pragma unroll
    for (int off = 1; off < 1024; off <<= 1) {
        int t = (tid >= off) ? sh[tid - off] : 0;
        __syncthreads();
        sh[tid] += t;
        __syncthreads();
    }
    if (tid < NBUCK) { int ex = sh[tid] - v; base_s[tid] = ex; cursor_s[tid] = ex; }
    if (tid == 0) base_s[NBUCK] = E;
}

__global__ __launch_bounds__(256) void k_binpass2(
    const int* __restrict__ src, const int* __restrict__ dst, const float* __restrict__ ew,
    int* __restrict__ cursor_d, int* __restrict__ cursor_s,
    int2* __restrict__ stage2, unsigned char* __restrict__ stage_s, int E) {
    __shared__ int cnt_d[NBUCK];
    __shared__ int gpos_d[NBUCK];
    __shared__ int cnt_s[NBUCK];
    __shared__ int gpos_s[NBUCK];

    int base = blockIdx.x * TILE;
    for (int i = threadIdx.x; i < NBUCK; i += 256) { cnt_d[i] = 0; cnt_s[i] = 0; }
    __syncthreads();

    int w0[16]; float w1[16]; int pd[16]; int rs[16];
#pragma unroll
    for (int k = 0; k < 16; ++k) {
        int idx = base + threadIdx.x + k * 256;
        pd[k] = -1;
        if (idx < E) {
            int s = src[idx], d = dst[idx];
            w1[k] = ew[idx];
            int bd = d >> BK_SHIFT;
            w0[k] = s | ((d & (BK_NODES - 1)) << 17);
            int rd = atomicAdd(&cnt_d[bd], 1);
            pd[k] = bd | (rd << 10);
            rs[k] = atomicAdd(&cnt_s[s >> BK_SHIFT], 1);
        }
    }
    __syncthreads();

    for (int i = threadIdx.x; i < NBUCK; i += 256) {
        int c = cnt_d[i]; if (c) gpos_d[i] = atomicAdd(&cursor_d[i], c);
        c = cnt_s[i];     if (c) gpos_s[i] = atomicAdd(&cursor_s[i], c);
    }
    __syncthreads();

#pragma unroll
    for (int k = 0; k < 16; ++k) {
        if (pd[k] >= 0) {
            int bd = pd[k] & 1023, rd = pd[k] >> 10;
            stage2[gpos_d[bd] + rd] = make_int2(w0[k], __float_as_int(w1[k]));
            int s = w0[k] & SRC_MASK;
            stage_s[gpos_s[s >> BK_SHIFT] + rs[k]] = (unsigned char)(s & (BK_NODES - 1));
        }
    }
}

__global__ __launch_bounds__(256) void k_prep_src(
    const int* __restrict__ base_s, const unsigned char* __restrict__ stage_s, const float* __restrict__ x,
    float* __restrict__ no, float* __restrict__ xs, int N) {
    __shared__ int cnt[BK_NODES];
    int b = blockIdx.x;
    int beg = base_s[b], end = base_s[b + 1];
    if (threadIdx.x < BK_NODES) cnt[threadIdx.x] = 0;
    __syncthreads();
    for (int j = beg + threadIdx.x; j < end; j += 256) atomicAdd(&cnt[stage_s[j]], 1);
    __syncthreads();
    if (threadIdx.x < BK_NODES) {
        int n = (b << BK_SHIFT) + threadIdx.x;
        if (n < N) {
            float nov = rsqrtf(fmaxf((float)cnt[threadIdx.x], 1.0f));
            no[n] = nov;
#pragma unroll
            for (int f = 0; f < 7; ++f) xs[n * 8 + f] = x[n * 7 + f] * nov;
            xs[n * 8 + 7] = 0.f;
        }
    }
}

__global__ __launch_bounds__(256) void k_scatter2(
    const int* __restrict__ base_d, const int2* __restrict__ stage2,
    int* __restrict__ row_ptr, float* __restrict__ ni,
    int* __restrict__ csr_src, float* __restrict__ csr_w, int N) {
    __shared__ int cnt[BK_NODES];
    __shared__ int scn[BK_NODES];
    __shared__ int cur[BK_NODES];
    int b = blockIdx.x;
    int beg = base_d[b], end = base_d[b + 1];
    if (threadIdx.x < BK_NODES) cnt[threadIdx.x] = 0;
    __syncthreads();
    for (int j = beg + threadIdx.x; j < end; j += 256) atomicAdd(&cnt[stage2[j].x >> 17], 1);
    __syncthreads();
    int v = (threadIdx.x < BK_NODES) ? cnt[threadIdx.x] : 0;
    if (threadIdx.x < BK_NODES) scn[threadIdx.x] = v;
    __syncthreads();
#pragma unroll
    for (int off = 1; off < BK_NODES; off <<= 1) {
        int t = (threadIdx.x < BK_NODES && threadIdx.x >= off) ? scn[threadIdx.x - off] : 0;
        __syncthreads();
        if (threadIdx.x < BK_NODES) scn[threadIdx.x] += t;
        __syncthreads();
    }
    if (threadIdx.x < BK_NODES) {
        int ex = scn[threadIdx.x] - v;
        cur[threadIdx.x] = beg + ex;
        int n = (b << BK_SHIFT) + threadIdx.x;
        if (n < N) {
            row_ptr[n] = beg + ex;
            ni[n] = rsqrtf(fmaxf((float)v, 1.0f));
        }
    }
    __syncthreads();
    for (int j = beg + threadIdx.x; j < end; j += 256) {
        int2 t = stage2[j];
        int dl = t.x >> 17;
        int pos = atomicAdd(&cur[dl], 1);
        csr_src[pos] = t.x & SRC_MASK;
        csr_w[pos] = __int_as_float(t.y);
    }
}

// ---------------- fused layers (node-major h[N][32]) ----------------

// layer 1: round-8 verbatim (node-major output).
__global__ __launch_bounds__(256) void k_layer1(
    const int* __restrict__ rp, const int* __restrict__ csr_src, const float* __restrict__ csr_w,
    const float* __restrict__ xs, const float* __restrict__ ni, const float* __restrict__ no,
    const float* __restrict__ W1, const float* __restrict__ b1, float* __restrict__ h1s, int N) {
    __shared__ float sW[7 * 32];
    __shared__ float sb[32];
    __shared__ float sh7[32][8];
    for (int i = threadIdx.x; i < 7 * 32; i += 256) sW[i] = W1[i];
    if (threadIdx.x < 32) sb[threadIdx.x] = b1[threadIdx.x];

    int g = threadIdx.x >> 3, lane = threadIdx.x & 7;
    int node = blockIdx.x * 32 + g;
    float acc = 0.f;
    if (node < N) {
        int beg = rp[node], end = rp[node + 1];
        for (int j0 = beg; j0 < end; j0 += 8) {
            int ms = 0; float mw = 0.f;
            if (j0 + lane < end) {
                ms = csr_src[j0 + lane];
                mw = csr_w[j0 + lane];
            }
            int m = end - j0; if (m > 8) m = 8;
            float a0 = 0.f, a1 = 0.f, a2 = 0.f, a3 = 0.f;
            int k = 0;
            for (; k + 4 <= m; k += 4) {
                int s0 = __shfl(ms, k, 8);     float w0 = __shfl(mw, k, 8);
                int s1 = __shfl(ms, k + 1, 8); float w1 = __shfl(mw, k + 1, 8);
                int s2 = __shfl(ms, k + 2, 8); float w2 = __shfl(mw, k + 2, 8);
                int s3 = __shfl(ms, k + 3, 8); float w3 = __shfl(mw, k + 3, 8);
                a0 += xs[s0 * 8 + lane] * w0;
                a1 += xs[s1 * 8 + lane] * w1;
                a2 += xs[s2 * 8 + lane] * w2;
                a3 += xs[s3 * 8 + lane] * w3;
            }
            for (; k < m; ++k) {
                int s = __shfl(ms, k, 8);
                float w = __shfl(mw, k, 8);
                a0 += xs[s * 8 + lane] * w;
            }
            acc += (a0 + a1) + (a2 + a3);
        }
        acc *= ni[node];
    }
    sh7[g][lane] = acc;
    __syncthreads();

    int g2 = threadIdx.x >> 5, l32 = threadIdx.x & 31;
#pragma unroll
    for (int t = 0; t < 4; ++t) {
        int nl = t * 8 + g2;
        int node2 = blockIdx.x * 32 + nl;
        if (node2 < N) {
            float o = sb[l32];
#pragma unroll
            for (int k = 0; k < 7; ++k) o += sh7[nl][k] * sW[k * 32 + l32];
            h1s[(size_t)node2 * 32 + l32] = fmaxf(o, 0.f) * no[node2];
        }
    }
}

// fused-gather aggregation: ONE WAVE PER NODE, 8 groups x 8 lanes, float4/lane.
// Each group's gather is one full 128B line; 4-slot unroll -> 32 lines in flight
// per wave before any consumption. Cross-group reduce via 3x shfl_xor.
// aggout[n][f] = (sum_e h_in[src_e][f]) * ni[n]
__global__ __launch_bounds__(256) void k_aggF(
    const int* __restrict__ rp, const int* __restrict__ csr_src, const float* __restrict__ h_in,
    const float* __restrict__ ni, float* __restrict__ aggout, int N) {
    int wave = threadIdx.x >> 6;       // 4 waves per block
    int lane = threadIdx.x & 63;
    int g = lane >> 3, sub = lane & 7;
    int node = blockIdx.x * 4 + wave;
    if (node >= N) return;
    int beg = rp[node], end = rp[node + 1];

    float4 A0 = make_float4(0.f, 0.f, 0.f, 0.f);
    float4 A1 = A0, A2 = A0, A3 = A0;
    int last = end - 1;

    for (int j0 = beg + g; j0 < end; j0 += 32) {
        int i1 = j0 + 8, i2 = j0 + 16, i3 = j0 + 24;
        // csr indices: clamp OOB slots to a valid index (value is a real node id)
        int s0 = csr_src[j0];
        int s1 = csr_src[i1 <= last ? i1 : last];
        int s2 = csr_src[i2 <= last ? i2 : last];
        int s3 = csr_src[i3 <= last ? i3 : last];
        // issue all 4 full-line gathers before consuming
        float4 v0 = *reinterpret_cast<const float4*>(&h_in[(size_t)s0 * 32 + sub * 4]);
        float4 v1 = *reinterpret_cast<const float4*>(&h_in[(size_t)s1 * 32 + sub * 4]);
        float4 v2 = *reinterpret_cast<const float4*>(&h_in[(size_t)s2 * 32 + sub * 4]);
        float4 v3 = *reinterpret_cast<const float4*>(&h_in[(size_t)s3 * 32 + sub * 4]);
        A0.x += v0.x; A0.y += v0.y; A0.z += v0.z; A0.w += v0.w;
        if (i1 < end) { A1.x += v1.x; A1.y += v1.y; A1.z += v1.z; A1.w += v1.w; }
        if (i2 < end) { A2.x += v2.x; A2.y += v2.y; A2.z += v2.z; A2.w += v2.w; }
        if (i3 < end) { A3.x += v3.x; A3.y += v3.y; A3.z += v3.z; A3.w += v3.w; }
    }

    float ax = (A0.x + A1.x) + (A2.x + A3.x);
    float ay = (A0.y + A1.y) + (A2.y + A3.y);
    float az = (A0.z + A1.z) + (A2.z + A3.z);
    float aw = (A0.w + A1.w) + (A2.w + A3.w);
#pragma unroll
    for (int off = 8; off <= 32; off <<= 1) {
        ax += __shfl_xor(ax, off, 64);
        ay += __shfl_xor(ay, off, 64);
        az += __shfl_xor(az, off, 64);
        aw += __shfl_xor(aw, off, 64);
    }
    if (g == 0) {
        float w = ni[node];
        float4 o = make_float4(ax * w, ay * w, az * w, aw * w);
        *reinterpret_cast<float4*>(&aggout[(size_t)node * 32 + sub * 4]) = o;
    }
}

// matmul epilogue for layer 2 (node-major, in-place safe).
__global__ __launch_bounds__(256) void k_mm2(
    const float* __restrict__ agg, const float* __restrict__ W, const float* __restrict__ bia,
    const float* __restrict__ no, float* __restrict__ h_out, int N) {
    __shared__ float sW[32 * 32];
    __shared__ float sb[32];
    __shared__ float shv[8][32];
    for (int i = threadIdx.x; i < 1024; i += 256) sW[i] = W[i];
    if (threadIdx.x < 32) sb[threadIdx.x] = bia[threadIdx.x];
    int g = threadIdx.x >> 5, lane = threadIdx.x & 31;
    int n = blockIdx.x * 8 + g;
    if (n < N) shv[g][lane] = agg[(size_t)n * 32 + lane];
    __syncthreads();
    if (n < N) {
        float o = sb[lane];
#pragma unroll
        for (int k = 0; k < 32; ++k) o += shv[g][k] * sW[k * 32 + lane];
        h_out[(size_t)n * 32 + lane] = fmaxf(o, 0.f) * no[n];
    }
}

// matmul epilogue for layer 3 + W4 pre-multiply -> h4pre.
__global__ __launch_bounds__(256) void k_mm3(
    const float* __restrict__ agg, const float* __restrict__ W3, const float* __restrict__ b3,
    const float* __restrict__ W4, const float* __restrict__ no, float2* __restrict__ h4pre, int N) {
    __shared__ float sW[32 * 32];
    __shared__ float sb[32];
    __shared__ float sW4[64];
    __shared__ float shv[8][32];
    for (int i = threadIdx.x; i < 1024; i += 256) sW[i] = W3[i];
    if (threadIdx.x < 32) sb[threadIdx.x] = b3[threadIdx.x];
    if (threadIdx.x < 64) sW4[threadIdx.x] = W4[threadIdx.x];
    int g = threadIdx.x >> 5, lane = threadIdx.x & 31;
    int n = blockIdx.x * 8 + g;
    if (n < N) shv[g][lane] = agg[(size_t)n * 32 + lane];
    __syncthreads();
    if (n < N) {
        float o = sb[lane];
#pragma unroll
        for (int k = 0; k < 32; ++k) o += shv[g][k] * sW[k * 32 + lane];
        float t = fmaxf(o, 0.f) * no[n];
        float px = t * sW4[lane * 2 + 0];
        float py = t * sW4[lane * 2 + 1];
#pragma unroll
        for (int off = 16; off; off >>= 1) {
            px += __shfl_xor(px, off, 32);
            py += __shfl_xor(py, off, 32);
        }
        if (lane == 0) h4pre[n] = make_float2(px, py);
    }
}

__global__ void k_agg4(const int* __restrict__ rp, const int* __restrict__ csr_src,
                       const float2* __restrict__ h4pre, const float* __restrict__ ni,
                       float2* __restrict__ agg2, int N) {
    int n = blockIdx.x * blockDim.x + threadIdx.x;
    if (n >= N) return;
    int beg = rp[n], end = rp[n + 1];
    float ax0 = 0.f, ay0 = 0.f, ax1 = 0.f, ay1 = 0.f;
    int j = beg;
    for (; j + 2 <= end; j += 2) {
        int s0 = csr_src[j], s1 = csr_src[j + 1];
        float2 v0 = h4pre[s0];
        float2 v1 = h4pre[s1];
        ax0 += v0.x; ay0 += v0.y;
        ax1 += v1.x; ay1 += v1.y;
    }
    if (j < end) {
        float2 v = h4pre[csr_src[j]];
        ax0 += v.x; ay0 += v.y;
    }
    float w = ni[n];
    agg2[n] = make_float2((ax0 + ax1) * w, (ay0 + ay1) * w);
}

__global__ void k_pool(const float2* __restrict__ agg2, const int* __restrict__ gid,
                       const float* __restrict__ b4, float* __restrict__ out, int N) {
    int g = blockIdx.x;
    int lo = 0, hi = N;
    while (lo < hi) { int m = (lo + hi) >> 1; if (gid[m] < g) lo = m + 1; else hi = m; }
    int start = lo;
    int lo2 = start, hi2 = N;
    while (lo2 < hi2) { int m = (lo2 + hi2) >> 1; if (gid[m] < g + 1) lo2 = m + 1; else hi2 = m; }
    int end = lo2;
    float sx = 0.f, sy = 0.f;
    for (int n = start + threadIdx.x; n < end; n += 64) {
        float2 v = agg2[n];
        sx += v.x;
        sy += v.y;
    }
#pragma unroll
    for (int off = 32; off; off >>= 1) {
        sx += __shfl_down(sx, off, 64);
        sy += __shfl_down(sy, off, 64);
    }
    if (threadIdx.x == 0) {
        int cnt = end - start;
        float inv = 1.0f / fmaxf((float)cnt, 1.0f);
        float scale = (float)cnt * inv;  // 0 if empty, else 1
        out[g * 2 + 0] = sx * inv + b4[0] * scale;
        out[g * 2 + 1] = sy * inv + b4[1] * scale;
    }
}

// ---------------- launch ----------------

extern "C" void kernel_launch(void* const* d_in, const int* in_sizes, int n_in,
                              void* d_out, int out_size, void* d_ws, size_t ws_size,
                              hipStream_t stream) {
    const float* x   = (const float*)d_in[0];
    const float* e   = (const float*)d_in[1];
    const float* W1  = (const float*)d_in[2];
    const float* b1  = (const float*)d_in[3];
    const float* W2  = (const float*)d_in[4];
    const float* b2  = (const float*)d_in[5];
    const float* W3  = (const float*)d_in[6];
    const float* b3  = (const float*)d_in[7];
    const float* W4  = (const float*)d_in[8];
    const float* b4  = (const float*)d_in[9];
    const int*   src = (const int*)d_in[10];
    const int*   dst = (const int*)d_in[11];
    const int*   gid = (const int*)d_in[12];
    float* out = (float*)d_out;

    const int N = NN, E = NE;
    const int G = out_size / 2;

    int* ws_i = (int*)d_ws;
    int* tot_d    = ws_i;                         // 1024
    int* tot_s    = ws_i + 1024;                  // 1024
    int* base_d   = ws_i + 2048;                  // 1024 (need 783)
    int* base_s   = ws_i + 3072;                  // 1024
    int* cursor_d = ws_i + 4096;                  // 1024
    int* cursor_s = ws_i + 5120;                  // 1024
    int* row_ptr  = ws_i + 6144;                  // N+4
    int* csr_src  = ws_i + 6144 + (size_t)N + 4;  // E
    float* csr_w  = (float*)(ws_i + 6144 + (size_t)N + 4 + (size_t)E); // E
    unsigned char* stage_s = (unsigned char*)csr_w;  // alias: dead before csr_w written

    float* fbase = (float*)(ws_i + 6144 + (size_t)N + 4 + 2 * (size_t)E);
    float* no_b  = fbase;                          // N
    float* ni_b  = fbase + (size_t)N;              // N
    float* xs    = fbase + (size_t)2 * N;          // 8N
    float* h1    = fbase + (size_t)10 * N;         // 32N (node-major [N][32])
    float* h2    = fbase + (size_t)42 * N;         // 32N (agg2 buffer, then h2 in-place)
    float2* h4pre = (float2*)(fbase + (size_t)74 * N); // 2N
    float2* agg2  = (float2*)(fbase + (size_t)76 * N); // 2N
    // stage2 aliased over h1/h2 (2E ints = 5M <= 64N; dead before layer1 writes h1)
    int2* stage2 = (int2*)(fbase + (size_t)10 * N);
    // layer-3 agg buffer reuses h1 (dead after layer-2 aggregation)
    float* agg3 = h1;

    // zero only the bucket-total arrays (8 KB)
    hipMemsetAsync(ws_i, 0, 2048 * sizeof(int), stream);

    k_tilecnt2<<<NTILES, 256, 0, stream>>>(src, dst, tot_d, tot_s, E);
    k_bucket_scan<<<1, 1024, 0, stream>>>(tot_d, tot_s, base_d, base_s, cursor_d, cursor_s, row_ptr, E);
    k_binpass2<<<NTILES, 256, 0, stream>>>(src, dst, e, cursor_d, cursor_s, stage2, stage_s, E);
    k_prep_src<<<NBUCK, 256, 0, stream>>>(base_s, stage_s, x, no_b, xs, N);
    k_scatter2<<<NBUCK, 256, 0, stream>>>(base_d, stage2, row_ptr, ni_b, csr_src, csr_w, N);

    k_layer1<<<(N + 31) / 32, 256, 0, stream>>>(row_ptr, csr_src, csr_w, xs, ni_b, no_b, W1, b1, h1, N);
    k_aggF<<<(N + 3) / 4, 256, 0, stream>>>(row_ptr, csr_src, h1, ni_b, h2, N);
    k_mm2<<<(N + 7) / 8, 256, 0, stream>>>(h2, W2, b2, no_b, h2, N);
    k_aggF<<<(N + 3) / 4, 256, 0, stream>>>(row_ptr, csr_src, h2, ni_b, agg3, N);
    k_mm3<<<(N + 7) / 8, 256, 0, stream>>>(agg3, W3, b3, W4, no_b, h4pre, N);
    k_agg4<<<(N + 255) / 256, 256, 0, stream>>>(row_ptr, csr_src, h4pre, ni_b, agg2, N);
    k_pool<<<G, 64, 0, stream>>>(agg2, gid, b4, out, N);
}

// Round 15
// 445.913 us; speedup vs baseline: 1.1066x; 1.0356x over previous
//
#include <hip/hip_runtime.h>

#define NN 100000
#define NE 2500000
#define BK_SHIFT 7
#define BK_NODES 128
#define NBUCK ((NN + BK_NODES - 1) / BK_NODES)   // 782
#define TILE 4096
#define NTILES ((NE + TILE - 1) / TILE)     // 611 (tilecnt2)
#define BTILE 8192
#define NBTILES ((NE + BTILE - 1) / BTILE)  // 306 (binpass2)
#define SRC_MASK 0x1FFFF                    // 17 bits, NN < 131072

// ---------------- CSR build: tile hist -> bucket totals -> scan -> direct-write binning ----------------

__global__ __launch_bounds__(256) void k_tilecnt2(const int* __restrict__ src,
                                                  const int* __restrict__ dst,
                                                  int* __restrict__ tot_d, int* __restrict__ tot_s,
                                                  int E) {
    __shared__ int cd[NBUCK];
    __shared__ int cs[NBUCK];
    int base = blockIdx.x * TILE;
    for (int i = threadIdx.x; i < NBUCK; i += 256) { cd[i] = 0; cs[i] = 0; }
    __syncthreads();
#pragma unroll
    for (int k = 0; k < 16; ++k) {
        int idx = base + threadIdx.x + k * 256;
        if (idx < E) {
            atomicAdd(&cd[dst[idx] >> BK_SHIFT], 1);
            atomicAdd(&cs[src[idx] >> BK_SHIFT], 1);
        }
    }
    __syncthreads();
    for (int i = threadIdx.x; i < NBUCK; i += 256) {
        int c = cd[i]; if (c) atomicAdd(&tot_d[i], c);
        c = cs[i];     if (c) atomicAdd(&tot_s[i], c);
    }
}

__global__ __launch_bounds__(1024) void k_bucket_scan(const int* __restrict__ tot_d,
                                                      const int* __restrict__ tot_s,
                                                      int* __restrict__ base_d, int* __restrict__ base_s,
                                                      int* __restrict__ cursor_d, int* __restrict__ cursor_s,
                                                      int* __restrict__ row_ptr, int E) {
    __shared__ int sh[1024];
    int tid = threadIdx.x;
    int v = (tid < NBUCK) ? tot_d[tid] : 0;
    sh[tid] = v;
    __syncthreads();
#pragma unroll
    for (int off = 1; off < 1024; off <<= 1) {
        int t = (tid >= off) ? sh[tid - off] : 0;
        __syncthreads();
        sh[tid] += t;
        __syncthreads();
    }
    if (tid < NBUCK) { int ex = sh[tid] - v; base_d[tid] = ex; cursor_d[tid] = ex; }
    if (tid == 0) { base_d[NBUCK] = E; row_ptr[NN] = E; }
    __syncthreads();
    v = (tid < NBUCK) ? tot_s[tid] : 0;
    sh[tid] = v;
    __syncthreads();
#pragma unroll
    for (int off = 1; off < 1024; off <<= 1) {
        int t = (tid >= off) ? sh[tid - off] : 0;
        __syncthreads();
        sh[tid] += t;
        __syncthreads();
    }
    if (tid < NBUCK) { int ex = sh[tid] - v; base_s[tid] = ex; cursor_s[tid] = ex; }
    if (tid == 0) base_s[NBUCK] = E;
}

// direct-write binning, 512 threads x 16 items = 8192 edges/tile.
// Longer per-(tile,bucket) runs -> fewer partial-line HBM writebacks.
__global__ __launch_bounds__(512) void k_binpass2(
    const int* __restrict__ src, const int* __restrict__ dst, const float* __restrict__ ew,
    int* __restrict__ cursor_d, int* __restrict__ cursor_s,
    int2* __restrict__ stage2, unsigned char* __restrict__ stage_s, int E) {
    __shared__ int cnt_d[NBUCK];
    __shared__ int gpos_d[NBUCK];
    __shared__ int cnt_s[NBUCK];
    __shared__ int gpos_s[NBUCK];

    int base = blockIdx.x * BTILE;
    for (int i = threadIdx.x; i < NBUCK; i += 512) { cnt_d[i] = 0; cnt_s[i] = 0; }
    __syncthreads();

    int w0[16]; float w1[16]; int pd[16]; int rs[16];
#pragma unroll
    for (int k = 0; k < 16; ++k) {
        int idx = base + threadIdx.x + k * 512;
        pd[k] = -1;
        if (idx < E) {
            int s = src[idx], d = dst[idx];
            w1[k] = ew[idx];
            int bd = d >> BK_SHIFT;
            w0[k] = s | ((d & (BK_NODES - 1)) << 17);
            int rd = atomicAdd(&cnt_d[bd], 1);
            pd[k] = bd | (rd << 10);      // rd <= 8191 -> 23 bits total, fits
            rs[k] = atomicAdd(&cnt_s[s >> BK_SHIFT], 1);
        }
    }
    __syncthreads();

    for (int i = threadIdx.x; i < NBUCK; i += 512) {
        int c = cnt_d[i]; if (c) gpos_d[i] = atomicAdd(&cursor_d[i], c);
        c = cnt_s[i];     if (c) gpos_s[i] = atomicAdd(&cursor_s[i], c);
    }
    __syncthreads();

#pragma unroll
    for (int k = 0; k < 16; ++k) {
        if (pd[k] >= 0) {
            int bd = pd[k] & 1023, rd = pd[k] >> 10;
            stage2[gpos_d[bd] + rd] = make_int2(w0[k], __float_as_int(w1[k]));
            int s = w0[k] & SRC_MASK;
            stage_s[gpos_s[s >> BK_SHIFT] + rs[k]] = (unsigned char)(s & (BK_NODES - 1));
        }
    }
}

__global__ __launch_bounds__(256) void k_prep_src(
    const int* __restrict__ base_s, const unsigned char* __restrict__ stage_s, const float* __restrict__ x,
    float* __restrict__ no, float* __restrict__ xs, int N) {
    __shared__ int cnt[BK_NODES];
    int b = blockIdx.x;
    int beg = base_s[b], end = base_s[b + 1];
    if (threadIdx.x < BK_NODES) cnt[threadIdx.x] = 0;
    __syncthreads();
    for (int j = beg + threadIdx.x; j < end; j += 256) atomicAdd(&cnt[stage_s[j]], 1);
    __syncthreads();
    if (threadIdx.x < BK_NODES) {
        int n = (b << BK_SHIFT) + threadIdx.x;
        if (n < N) {
            float nov = rsqrtf(fmaxf((float)cnt[threadIdx.x], 1.0f));
            no[n] = nov;
#pragma unroll
            for (int f = 0; f < 7; ++f) xs[n * 8 + f] = x[n * 7 + f] * nov;
            xs[n * 8 + 7] = 0.f;
        }
    }
}

__global__ __launch_bounds__(256) void k_scatter2(
    const int* __restrict__ base_d, const int2* __restrict__ stage2,
    int* __restrict__ row_ptr, float* __restrict__ ni,
    int* __restrict__ csr_src, float* __restrict__ csr_w, int N) {
    __shared__ int cnt[BK_NODES];
    __shared__ int scn[BK_NODES];
    __shared__ int cur[BK_NODES];
    int b = blockIdx.x;
    int beg = base_d[b], end = base_d[b + 1];
    if (threadIdx.x < BK_NODES) cnt[threadIdx.x] = 0;
    __syncthreads();
    for (int j = beg + threadIdx.x; j < end; j += 256) atomicAdd(&cnt[stage2[j].x >> 17], 1);
    __syncthreads();
    int v = (threadIdx.x < BK_NODES) ? cnt[threadIdx.x] : 0;
    if (threadIdx.x < BK_NODES) scn[threadIdx.x] = v;
    __syncthreads();
#pragma unroll
    for (int off = 1; off < BK_NODES; off <<= 1) {
        int t = (threadIdx.x < BK_NODES && threadIdx.x >= off) ? scn[threadIdx.x - off] : 0;
        __syncthreads();
        if (threadIdx.x < BK_NODES) scn[threadIdx.x] += t;
        __syncthreads();
    }
    if (threadIdx.x < BK_NODES) {
        int ex = scn[threadIdx.x] - v;
        cur[threadIdx.x] = beg + ex;
        int n = (b << BK_SHIFT) + threadIdx.x;
        if (n < N) {
            row_ptr[n] = beg + ex;
            ni[n] = rsqrtf(fmaxf((float)v, 1.0f));
        }
    }
    __syncthreads();
    for (int j = beg + threadIdx.x; j < end; j += 256) {
        int2 t = stage2[j];
        int dl = t.x >> 17;
        int pos = atomicAdd(&cur[dl], 1);
        csr_src[pos] = t.x & SRC_MASK;
        csr_w[pos] = __int_as_float(t.y);
    }
}

// ---------------- fused layers (node-major h[N][32]) ----------------

__global__ __launch_bounds__(256) void k_layer1(
    const int* __restrict__ rp, const int* __restrict__ csr_src, const float* __restrict__ csr_w,
    const float* __restrict__ xs, const float* __restrict__ ni, const float* __restrict__ no,
    const float* __restrict__ W1, const float* __restrict__ b1, float* __restrict__ h1s, int N) {
    __shared__ float sW[7 * 32];
    __shared__ float sb[32];
    __shared__ float sh7[32][8];
    for (int i = threadIdx.x; i < 7 * 32; i += 256) sW[i] = W1[i];
    if (threadIdx.x < 32) sb[threadIdx.x] = b1[threadIdx.x];

    int g = threadIdx.x >> 3, lane = threadIdx.x & 7;
    int node = blockIdx.x * 32 + g;
    float acc = 0.f;
    if (node < N) {
        int beg = rp[node], end = rp[node + 1];
        for (int j0 = beg; j0 < end; j0 += 8) {
            int ms = 0; float mw = 0.f;
            if (j0 + lane < end) {
                ms = csr_src[j0 + lane];
                mw = csr_w[j0 + lane];
            }
            int m = end - j0; if (m > 8) m = 8;
            float a0 = 0.f, a1 = 0.f, a2 = 0.f, a3 = 0.f;
            int k = 0;
            for (; k + 4 <= m; k += 4) {
                int s0 = __shfl(ms, k, 8);     float w0 = __shfl(mw, k, 8);
                int s1 = __shfl(ms, k + 1, 8); float w1 = __shfl(mw, k + 1, 8);
                int s2 = __shfl(ms, k + 2, 8); float w2 = __shfl(mw, k + 2, 8);
                int s3 = __shfl(ms, k + 3, 8); float w3 = __shfl(mw, k + 3, 8);
                a0 += xs[s0 * 8 + lane] * w0;
                a1 += xs[s1 * 8 + lane] * w1;
                a2 += xs[s2 * 8 + lane] * w2;
                a3 += xs[s3 * 8 + lane] * w3;
            }
            for (; k < m; ++k) {
                int s = __shfl(ms, k, 8);
                float w = __shfl(mw, k, 8);
                a0 += xs[s * 8 + lane] * w;
            }
            acc += (a0 + a1) + (a2 + a3);
        }
        acc *= ni[node];
    }
    sh7[g][lane] = acc;
    __syncthreads();

    int g2 = threadIdx.x >> 5, l32 = threadIdx.x & 31;
#pragma unroll
    for (int t = 0; t < 4; ++t) {
        int nl = t * 8 + g2;
        int node2 = blockIdx.x * 32 + nl;
        if (node2 < N) {
            float o = sb[l32];
#pragma unroll
            for (int k = 0; k < 7; ++k) o += sh7[nl][k] * sW[k * 32 + l32];
            h1s[(size_t)node2 * 32 + l32] = fmaxf(o, 0.f) * no[node2];
        }
    }
}

// fused-gather aggregation: ONE WAVE PER NODE, 8 groups x 8 lanes, float4/lane.
__global__ __launch_bounds__(256) void k_aggF(
    const int* __restrict__ rp, const int* __restrict__ csr_src, const float* __restrict__ h_in,
    const float* __restrict__ ni, float* __restrict__ aggout, int N) {
    int wave = threadIdx.x >> 6;       // 4 waves per block
    int lane = threadIdx.x & 63;
    int g = lane >> 3, sub = lane & 7;
    int node = blockIdx.x * 4 + wave;
    if (node >= N) return;
    int beg = rp[node], end = rp[node + 1];

    float4 A0 = make_float4(0.f, 0.f, 0.f, 0.f);
    float4 A1 = A0, A2 = A0, A3 = A0;
    int last = end - 1;

    for (int j0 = beg + g; j0 < end; j0 += 32) {
        int i1 = j0 + 8, i2 = j0 + 16, i3 = j0 + 24;
        int s0 = csr_src[j0];
        int s1 = csr_src[i1 <= last ? i1 : last];
        int s2 = csr_src[i2 <= last ? i2 : last];
        int s3 = csr_src[i3 <= last ? i3 : last];
        float4 v0 = *reinterpret_cast<const float4*>(&h_in[(size_t)s0 * 32 + sub * 4]);
        float4 v1 = *reinterpret_cast<const float4*>(&h_in[(size_t)s1 * 32 + sub * 4]);
        float4 v2 = *reinterpret_cast<const float4*>(&h_in[(size_t)s2 * 32 + sub * 4]);
        float4 v3 = *reinterpret_cast<const float4*>(&h_in[(size_t)s3 * 32 + sub * 4]);
        A0.x += v0.x; A0.y += v0.y; A0.z += v0.z; A0.w += v0.w;
        if (i1 < end) { A1.x += v1.x; A1.y += v1.y; A1.z += v1.z; A1.w += v1.w; }
        if (i2 < end) { A2.x += v2.x; A2.y += v2.y; A2.z += v2.z; A2.w += v2.w; }
        if (i3 < end) { A3.x += v3.x; A3.y += v3.y; A3.z += v3.z; A3.w += v3.w; }
    }

    float ax = (A0.x + A1.x) + (A2.x + A3.x);
    float ay = (A0.y + A1.y) + (A2.y + A3.y);
    float az = (A0.z + A1.z) + (A2.z + A3.z);
    float aw = (A0.w + A1.w) + (A2.w + A3.w);
#pragma unroll
    for (int off = 8; off <= 32; off <<= 1) {
        ax += __shfl_xor(ax, off, 64);
        ay += __shfl_xor(ay, off, 64);
        az += __shfl_xor(az, off, 64);
        aw += __shfl_xor(aw, off, 64);
    }
    if (g == 0) {
        float w = ni[node];
        float4 o = make_float4(ax * w, ay * w, az * w, aw * w);
        *reinterpret_cast<float4*>(&aggout[(size_t)node * 32 + sub * 4]) = o;
    }
}

__global__ __launch_bounds__(256) void k_mm2(
    const float* __restrict__ agg, const float* __restrict__ W, const float* __restrict__ bia,
    const float* __restrict__ no, float* __restrict__ h_out, int N) {
    __shared__ float sW[32 * 32];
    __shared__ float sb[32];
    __shared__ float shv[8][32];
    for (int i = threadIdx.x; i < 1024; i += 256) sW[i] = W[i];
    if (threadIdx.x < 32) sb[threadIdx.x] = bia[threadIdx.x];
    int g = threadIdx.x >> 5, lane = threadIdx.x & 31;
    int n = blockIdx.x * 8 + g;
    if (n < N) shv[g][lane] = agg[(size_t)n * 32 + lane];
    __syncthreads();
    if (n < N) {
        float o = sb[lane];
#pragma unroll
        for (int k = 0; k < 32; ++k) o += shv[g][k] * sW[k * 32 + lane];
        h_out[(size_t)n * 32 + lane] = fmaxf(o, 0.f) * no[n];
    }
}

__global__ __launch_bounds__(256) void k_mm3(
    const float* __restrict__ agg, const float* __restrict__ W3, const float* __restrict__ b3,
    const float* __restrict__ W4, const float* __restrict__ no, float2* __restrict__ h4pre, int N) {
    __shared__ float sW[32 * 32];
    __shared__ float sb[32];
    __shared__ float sW4[64];
    __shared__ float shv[8][32];
    for (int i = threadIdx.x; i < 1024; i += 256) sW[i] = W3[i];
    if (threadIdx.x < 32) sb[threadIdx.x] = b3[threadIdx.x];
    if (threadIdx.x < 64) sW4[threadIdx.x] = W4[threadIdx.x];
    int g = threadIdx.x >> 5, lane = threadIdx.x & 31;
    int n = blockIdx.x * 8 + g;
    if (n < N) shv[g][lane] = agg[(size_t)n * 32 + lane];
    __syncthreads();
    if (n < N) {
        float o = sb[lane];
#pragma unroll
        for (int k = 0; k < 32; ++k) o += shv[g][k] * sW[k * 32 + lane];
        float t = fmaxf(o, 0.f) * no[n];
        float px = t * sW4[lane * 2 + 0];
        float py = t * sW4[lane * 2 + 1];
#pragma unroll
        for (int off = 16; off; off >>= 1) {
            px += __shfl_xor(px, off, 32);
            py += __shfl_xor(py, off, 32);
        }
        if (lane == 0) h4pre[n] = make_float2(px, py);
    }
}

__global__ void k_agg4(const int* __restrict__ rp, const int* __restrict__ csr_src,
                       const float2* __restrict__ h4pre, const float* __restrict__ ni,
                       float2* __restrict__ agg2, int N) {
    int n = blockIdx.x * blockDim.x + threadIdx.x;
    if (n >= N) return;
    int beg = rp[n], end = rp[n + 1];
    float ax0 = 0.f, ay0 = 0.f, ax1 = 0.f, ay1 = 0.f;
    int j = beg;
    for (; j + 2 <= end; j += 2) {
        int s0 = csr_src[j], s1 = csr_src[j + 1];
        float2 v0 = h4pre[s0];
        float2 v1 = h4pre[s1];
        ax0 += v0.x; ay0 += v0.y;
        ax1 += v1.x; ay1 += v1.y;
    }
    if (j < end) {
        float2 v = h4pre[csr_src[j]];
        ax0 += v.x; ay0 += v.y;
    }
    float w = ni[n];
    agg2[n] = make_float2((ax0 + ax1) * w, (ay0 + ay1) * w);
}

__global__ void k_pool(const float2* __restrict__ agg2, const int* __restrict__ gid,
                       const float* __restrict__ b4, float* __restrict__ out, int N) {
    int g = blockIdx.x;
    int lo = 0, hi = N;
    while (lo < hi) { int m = (lo + hi) >> 1; if (gid[m] < g) lo = m + 1; else hi = m; }
    int start = lo;
    int lo2 = start, hi2 = N;
    while (lo2 < hi2) { int m = (lo2 + hi2) >> 1; if (gid[m] < g + 1) lo2 = m + 1; else hi2 = m; }
    int end = lo2;
    float sx = 0.f, sy = 0.f;
    for (int n = start + threadIdx.x; n < end; n += 64) {
        float2 v = agg2[n];
        sx += v.x;
        sy += v.y;
    }
#pragma unroll
    for (int off = 32; off; off >>= 1) {
        sx += __shfl_down(sx, off, 64);
        sy += __shfl_down(sy, off, 64);
    }
    if (threadIdx.x == 0) {
        int cnt = end - start;
        float inv = 1.0f / fmaxf((float)cnt, 1.0f);
        float scale = (float)cnt * inv;  // 0 if empty, else 1
        out[g * 2 + 0] = sx * inv + b4[0] * scale;
        out[g * 2 + 1] = sy * inv + b4[1] * scale;
    }
}

// ---------------- launch ----------------

extern "C" void kernel_launch(void* const* d_in, const int* in_sizes, int n_in,
                              void* d_out, int out_size, void* d_ws, size_t ws_size,
                              hipStream_t stream) {
    const float* x   = (const float*)d_in[0];
    const float* e   = (const float*)d_in[1];
    const float* W1  = (const float*)d_in[2];
    const float* b1  = (const float*)d_in[3];
    const float* W2  = (const float*)d_in[4];
    const float* b2  = (const float*)d_in[5];
    const float* W3  = (const float*)d_in[6];
    const float* b3  = (const float*)d_in[7];
    const float* W4  = (const float*)d_in[8];
    const float* b4  = (const float*)d_in[9];
    const int*   src = (const int*)d_in[10];
    const int*   dst = (const int*)d_in[11];
    const int*   gid = (const int*)d_in[12];
    float* out = (float*)d_out;

    const int N = NN, E = NE;
    const int G = out_size / 2;

    int* ws_i = (int*)d_ws;
    int* tot_d    = ws_i;                         // 1024
    int* tot_s    = ws_i + 1024;                  // 1024
    int* base_d   = ws_i + 2048;                  // 1024 (need 783)
    int* base_s   = ws_i + 3072;                  // 1024
    int* cursor_d = ws_i + 4096;                  // 1024
    int* cursor_s = ws_i + 5120;                  // 1024
    int* row_ptr  = ws_i + 6144;                  // N+4
    int* csr_src  = ws_i + 6144 + (size_t)N + 4;  // E
    float* csr_w  = (float*)(ws_i + 6144 + (size_t)N + 4 + (size_t)E); // E
    unsigned char* stage_s = (unsigned char*)csr_w;  // alias: dead before csr_w written

    float* fbase = (float*)(ws_i + 6144 + (size_t)N + 4 + 2 * (size_t)E);
    float* no_b  = fbase;                          // N
    float* ni_b  = fbase + (size_t)N;              // N
    float* xs    = fbase + (size_t)2 * N;          // 8N
    float* h1    = fbase + (size_t)10 * N;         // 32N (node-major [N][32])
    float* h2    = fbase + (size_t)42 * N;         // 32N (agg buffer, then h2 in-place)
    float2* h4pre = (float2*)(fbase + (size_t)74 * N); // 2N
    float2* agg2  = (float2*)(fbase + (size_t)76 * N); // 2N
    // stage2 aliased over h1/h2 (2E ints = 5M <= 64N; dead before layer1 writes h1)
    int2* stage2 = (int2*)(fbase + (size_t)10 * N);
    // layer-3 agg buffer reuses h1 (dead after layer-2 aggregation)
    float* agg3 = h1;

    // zero only the bucket-total arrays (8 KB)
    hipMemsetAsync(ws_i, 0, 2048 * sizeof(int), stream);

    k_tilecnt2<<<NTILES, 256, 0, stream>>>(src, dst, tot_d, tot_s, E);
    k_bucket_scan<<<1, 1024, 0, stream>>>(tot_d, tot_s, base_d, base_s, cursor_d, cursor_s, row_ptr, E);
    k_binpass2<<<NBTILES, 512, 0, stream>>>(src, dst, e, cursor_d, cursor_s, stage2, stage_s, E);
    k_prep_src<<<NBUCK, 256, 0, stream>>>(base_s, stage_s, x, no_b, xs, N);
    k_scatter2<<<NBUCK, 256, 0, stream>>>(base_d, stage2, row_ptr, ni_b, csr_src, csr_w, N);

    k_layer1<<<(N + 31) / 32, 256, 0, stream>>>(row_ptr, csr_src, csr_w, xs, ni_b, no_b, W1, b1, h1, N);
    k_aggF<<<(N + 3) / 4, 256, 0, stream>>>(row_ptr, csr_src, h1, ni_b, h2, N);
    k_mm2<<<(N + 7) / 8, 256, 0, stream>>>(h2, W2, b2, no_b, h2, N);
    k_aggF<<<(N + 3) / 4, 256, 0, stream>>>(row_ptr, csr_src, h2, ni_b, agg3, N);
    k_mm3<<<(N + 7) / 8, 256, 0, stream>>>(agg3, W3, b3, W4, no_b, h4pre, N);
    k_agg4<<<(N + 255) / 256, 256, 0, stream>>>(row_ptr, csr_src, h4pre, ni_b, agg2, N);
    k_pool<<<G, 64, 0, stream>>>(agg2, gid, b4, out, N);
}